// Round 1
// baseline (196.815 us; speedup 1.0000x reference)
//
#include <hip/hip_runtime.h>

#define EPSF 1e-8f

// Layouts in workspace (all float32):
//   x    [b][h][w][nj][cj][ci]   loc = (b*32+h)*32+w, 4096 floats/loc   (128 MiB)
//   B    [loc][cj*32+ci]         1024 floats/loc                        (32 MiB)
//   shat [loc][nj*32+cj]         128 floats/loc                         (4 MiB)
//   pm/ps/pt [bh=256][ci=32]     softmax partials
//   sm/siz   [b=8][ci=32]        softmax max / 1/Z
// Total ~172 MB of d_ws.

// ---------------------------------------------------------------------------
// Conv: effectively Cin=3 (n_i 0..2), Cout=128, 3x3, pad 1, per (b, ci) image.
// x[b,h,w,nj,cj,ci] = sum_{kd,ky,kx} w[cj*4+nj,kd,ky,kx]*in[b,ci,kd,h+ky-1,w+kx-1] + bias
// block = (b,h), 1024 threads = 32 w-positions x 32 ci. c-loop is wave-uniform
// so weights become s_loads; stores are ci-contiguous (coalesced, the expensive side).
__global__ __launch_bounds__(1024) void k_conv(const float* __restrict__ in,
                                               const float* __restrict__ cw,
                                               const float* __restrict__ cb,
                                               float* __restrict__ x) {
    const int b = blockIdx.x >> 5;
    const int h = blockIdx.x & 31;
    const int t = threadIdx.x;
    const int ci = t & 31;
    const int w = t >> 5;

    float v[27];
#pragma unroll
    for (int kd = 0; kd < 3; ++kd) {
#pragma unroll
        for (int dy = 0; dy < 3; ++dy) {
            const int y = h + dy - 1;
            const bool yok = (y >= 0) && (y < 32);
#pragma unroll
            for (int dx = 0; dx < 3; ++dx) {
                const int xx = w + dx - 1;
                float val = 0.0f;
                if (yok && xx >= 0 && xx < 32)
                    val = in[(((size_t)(b * 32 + ci) * 8 + kd) * 32 + y) * 32 + xx];
                v[kd * 9 + dy * 3 + dx] = val;
            }
        }
    }

    float* xloc = x + ((size_t)blockIdx.x * 32 + w) * 4096;
    for (int c = 0; c < 128; ++c) {          // wave-uniform -> scalar weight loads
        const float* wc = cw + c * 27;
        float acc = cb[c];
#pragma unroll
        for (int k = 0; k < 27; ++k) acc = fmaf(wc[k], v[k], acc);
        const int cj = c >> 2, nj = c & 3;
        xloc[(nj * 32 + cj) * 32 + ci] = acc;
    }
}

// ---------------------------------------------------------------------------
// Iteration 0: B=0 -> k exactly uniform (1/32768). Fused S, squash, B1.
// 256 threads handle 2 locations; 128 threads/loc, thread = u = nj*32+cj.
// LDS [u][33] padding: phase-1 writes land on bank (u+ci)&31 (2-way, free),
// phase-2 reads on bank (cj+ci)&31 (2-way, free).
__global__ __launch_bounds__(256) void k_iter0(const float* __restrict__ x,
                                               float* __restrict__ B) {
    __shared__ float p[2][128][33];
    const int t = threadIdx.x;
    const int l = t >> 7;
    const int u = t & 127;
    const size_t loc = (size_t)blockIdx.x * 2 + l;

    const float4* xr = reinterpret_cast<const float4*>(x + loc * 4096 + (size_t)u * 32);
    float xv[32];
#pragma unroll
    for (int j = 0; j < 8; ++j) {
        float4 f = xr[j];
        xv[4 * j + 0] = f.x; xv[4 * j + 1] = f.y; xv[4 * j + 2] = f.z; xv[4 * j + 3] = f.w;
    }
    float S = 0.0f;
#pragma unroll
    for (int c = 0; c < 32; ++c) S += xv[c];
    S *= (1.0f / 32768.0f);
    const float sh = fabsf(S) * S / (1.0f + S * S + EPSF);   // squash (last dim size 1)

#pragma unroll
    for (int c = 0; c < 32; ++c) p[l][u][c] = sh * xv[c];
    __syncthreads();
#pragma unroll
    for (int r = 0; r < 8; ++r) {
        const int pair = t + r * 256;                 // 0..2047
        const int l2 = pair >> 10, q = pair & 1023;   // q = cj*32+ci
        const int cj = q >> 5, ci = q & 31;
        const float s = p[l2][cj][ci] + p[l2][32 + cj][ci] +
                        p[l2][64 + cj][ci] + p[l2][96 + cj][ci];
        B[((size_t)blockIdx.x * 2 + l2) * 1024 + q] = s;      // B starts at 0
    }
}

// ---------------------------------------------------------------------------
// Softmax stats partials: block = (b,h) reduces its 32768-elem slice of B
// into per-ci {max, sum e^{v-m}, sum e^{v-m}(v-m)}.
__global__ __launch_bounds__(256) void k_stats_part(const float* __restrict__ B,
                                                    float* __restrict__ pm,
                                                    float* __restrict__ ps,
                                                    float* __restrict__ pt) {
    const int bh = blockIdx.x;
    const int t = threadIdx.x;
    const float4* Bp = reinterpret_cast<const float4*>(B) + (size_t)bh * 8192;

    float m0 = -1e30f, m1 = -1e30f, m2 = -1e30f, m3 = -1e30f;
#pragma unroll 4
    for (int j = 0; j < 32; ++j) {
        float4 f = Bp[t + j * 256];
        m0 = fmaxf(m0, f.x); m1 = fmaxf(m1, f.y); m2 = fmaxf(m2, f.z); m3 = fmaxf(m3, f.w);
    }
    __shared__ float red[32][33];
    __shared__ float bm[32];
    const int ciq = (t & 7) * 4, copy = t >> 3;
    red[ciq + 0][copy] = m0; red[ciq + 1][copy] = m1;
    red[ciq + 2][copy] = m2; red[ciq + 3][copy] = m3;
    __syncthreads();
    if (t < 32) {
        float M = red[t][0];
        for (int c = 1; c < 32; ++c) M = fmaxf(M, red[t][c]);
        bm[t] = M;
    }
    __syncthreads();
    const float M0 = bm[ciq], M1 = bm[ciq + 1], M2 = bm[ciq + 2], M3 = bm[ciq + 3];

    float s0 = 0, s1 = 0, s2 = 0, s3 = 0, T0 = 0, T1 = 0, T2 = 0, T3 = 0;
#pragma unroll 4
    for (int j = 0; j < 32; ++j) {
        float4 f = Bp[t + j * 256];
        float d, e;
        d = f.x - M0; e = expf(d); s0 += e; T0 += e * d;
        d = f.y - M1; e = expf(d); s1 += e; T1 += e * d;
        d = f.z - M2; e = expf(d); s2 += e; T2 += e * d;
        d = f.w - M3; e = expf(d); s3 += e; T3 += e * d;
    }
    __syncthreads();
    red[ciq + 0][copy] = s0; red[ciq + 1][copy] = s1;
    red[ciq + 2][copy] = s2; red[ciq + 3][copy] = s3;
    __syncthreads();
    if (t < 32) {
        float S = 0;
        for (int c = 0; c < 32; ++c) S += red[t][c];
        ps[bh * 32 + t] = S;
        pm[bh * 32 + t] = bm[t];
    }
    __syncthreads();
    red[ciq + 0][copy] = T0; red[ciq + 1][copy] = T1;
    red[ciq + 2][copy] = T2; red[ciq + 3][copy] = T3;
    __syncthreads();
    if (t < 32) {
        float S = 0;
        for (int c = 0; c < 32; ++c) S += red[t][c];
        pt[bh * 32 + t] = S;
    }
}

// Combine 32 h-partials per (b,ci); optionally emit normalized entropy scalar.
__global__ __launch_bounds__(256) void k_stats_comb(const float* __restrict__ pm,
                                                    const float* __restrict__ ps,
                                                    const float* __restrict__ pt,
                                                    float* __restrict__ sm,
                                                    float* __restrict__ siz,
                                                    float* __restrict__ d_ent,
                                                    int final_) {
    const int t = threadIdx.x;            // t = b*32+ci
    const int b = t >> 5, ci = t & 31;
    float M = -1e30f;
    for (int h = 0; h < 32; ++h) M = fmaxf(M, pm[(b * 32 + h) * 32 + ci]);
    float Z = 0.0f, T = 0.0f;
    for (int h = 0; h < 32; ++h) {
        const int i = (b * 32 + h) * 32 + ci;
        const float dm = pm[i] - M;
        const float e = expf(dm);
        Z += ps[i] * e;
        T += e * (pt[i] + ps[i] * dm);
    }
    sm[t] = M;
    siz[t] = 1.0f / Z;
    if (final_) {
        // ent = -sum p log p = logZ - T/Z  (eps-in-log effect ~3e-5, << 2e-2 tol)
        const float ent = (logf(Z) - T / Z) / logf(32768.0f);
        __shared__ float red[256];
        red[t] = ent;
        __syncthreads();
        for (int s2 = 128; s2 > 0; s2 >>= 1) {
            if (t < s2) red[t] += red[t + s2];
            __syncthreads();
        }
        if (t == 0) *d_ent = red[0] * (1.0f / 256.0f);
    }
}

// ---------------------------------------------------------------------------
// Routing iteration (i>=1): k = exp(B-m)/Z on the fly, S, squash; then either
// B += sum_nj sh*x (FINAL=0) or write S_hat (FINAL=1).
template <int FINAL>
__global__ __launch_bounds__(256) void k_iter(const float* __restrict__ x,
                                              float* __restrict__ B,
                                              const float* __restrict__ sm,
                                              const float* __restrict__ siz,
                                              float* __restrict__ shat) {
    __shared__ float s_m[32], s_z[32];
    __shared__ float p[2][128][33];
    const int t = threadIdx.x;
    const int bb = (int)(((size_t)blockIdx.x * 2) >> 10);    // batch index
    if (t < 32) { s_m[t] = sm[bb * 32 + t]; s_z[t] = siz[bb * 32 + t]; }
    __syncthreads();

    const int l = t >> 7;
    const int u = t & 127;          // nj*32+cj
    const int cj = u & 31;
    const size_t loc = (size_t)blockIdx.x * 2 + l;

    const float4* xr = reinterpret_cast<const float4*>(x + loc * 4096 + (size_t)u * 32);
    const float4* Br = reinterpret_cast<const float4*>(B + loc * 1024 + (size_t)cj * 32);
    float xv[32];
#pragma unroll
    for (int j = 0; j < 8; ++j) {
        float4 f = xr[j];
        xv[4 * j + 0] = f.x; xv[4 * j + 1] = f.y; xv[4 * j + 2] = f.z; xv[4 * j + 3] = f.w;
    }
    float S = 0.0f;
#pragma unroll
    for (int j = 0; j < 8; ++j) {
        float4 bf = Br[j];
        S = fmaf(expf(bf.x - s_m[4 * j + 0]) * s_z[4 * j + 0], xv[4 * j + 0], S);
        S = fmaf(expf(bf.y - s_m[4 * j + 1]) * s_z[4 * j + 1], xv[4 * j + 1], S);
        S = fmaf(expf(bf.z - s_m[4 * j + 2]) * s_z[4 * j + 2], xv[4 * j + 2], S);
        S = fmaf(expf(bf.w - s_m[4 * j + 3]) * s_z[4 * j + 3], xv[4 * j + 3], S);
    }
    const float sh = fabsf(S) * S / (1.0f + S * S + EPSF);

    if constexpr (FINAL) {
        shat[loc * 128 + u] = sh;
    } else {
#pragma unroll
        for (int c = 0; c < 32; ++c) p[l][u][c] = sh * xv[c];
        __syncthreads();
#pragma unroll
        for (int r = 0; r < 8; ++r) {
            const int pair = t + r * 256;
            const int l2 = pair >> 10, q = pair & 1023;
            const int cjq = q >> 5, ciq = q & 31;
            const size_t idx = ((size_t)blockIdx.x * 2 + l2) * 1024 + q;
            B[idx] += p[l2][cjq][ciq] + p[l2][32 + cjq][ciq] +
                      p[l2][64 + cjq][ciq] + p[l2][96 + cjq][ciq];
        }
    }
}

// ---------------------------------------------------------------------------
// shat [b][h][w][nj*32+cj]  ->  out [b][cj*4+nj][h][w]
__global__ __launch_bounds__(256) void k_out(const float* __restrict__ shat,
                                             float* __restrict__ out) {
    __shared__ float tile[32][129];   // [w][u]
    const int bh = blockIdx.x;
    const int b = bh >> 5, h = bh & 31;
    const int t = threadIdx.x;
    const float4* sp = reinterpret_cast<const float4*>(shat + (size_t)bh * 4096);
#pragma unroll
    for (int j = 0; j < 4; ++j) {
        const int idx = t + j * 256;           // f4 index, 0..1023
        const float4 f = sp[idx];
        const int w = idx >> 5;
        const int u4 = (idx & 31) * 4;
        tile[w][u4 + 0] = f.x; tile[w][u4 + 1] = f.y;
        tile[w][u4 + 2] = f.z; tile[w][u4 + 3] = f.w;
    }
    __syncthreads();
    const int cp = t >> 1, half = t & 1;            // cp = cj*4+nj
    const int u = (cp & 3) * 32 + (cp >> 2);        // nj*32+cj
    float* op = out + (((size_t)b * 128 + cp) * 32 + h) * 32 + half * 16;
#pragma unroll
    for (int j = 0; j < 16; ++j) op[j] = tile[half * 16 + j][u];
}

// ---------------------------------------------------------------------------
extern "C" void kernel_launch(void* const* d_in, const int* in_sizes, int n_in,
                              void* d_out, int out_size, void* d_ws, size_t ws_size,
                              hipStream_t stream) {
    const float* in = (const float*)d_in[0];   // (8,32,8,32,32)
    const float* cw = (const float*)d_in[1];   // (128,1,3,3,3)
    const float* cb = (const float*)d_in[2];   // (128,)
    float* out = (float*)d_out;                // 1048576 + 1 floats

    float* x    = (float*)d_ws;                // 33,554,432 f
    float* B    = x + 33554432;                //  8,388,608 f
    float* shat = B + 8388608;                 //  1,048,576 f
    float* pm   = shat + 1048576;              //      8,192 f
    float* ps   = pm + 8192;
    float* pt   = ps + 8192;
    float* sm   = pt + 8192;                   //        256 f
    float* siz  = sm + 256;                    // total ~172 MB

    k_conv<<<256, 1024, 0, stream>>>(in, cw, cb, x);
    k_iter0<<<4096, 256, 0, stream>>>(x, B);                               // -> B1
    k_stats_part<<<256, 256, 0, stream>>>(B, pm, ps, pt);
    k_stats_comb<<<1, 256, 0, stream>>>(pm, ps, pt, sm, siz, out + 1048576, 0);
    k_iter<0><<<4096, 256, 0, stream>>>(x, B, sm, siz, nullptr);           // -> B2
    k_stats_part<<<256, 256, 0, stream>>>(B, pm, ps, pt);
    k_stats_comb<<<1, 256, 0, stream>>>(pm, ps, pt, sm, siz, out + 1048576, 1); // + entropy
    k_iter<1><<<4096, 256, 0, stream>>>(x, B, sm, siz, shat);              // -> S_hat
    k_out<<<256, 256, 0, stream>>>(shat, out);
}

// Round 2
// 157.928 us; speedup vs baseline: 1.2462x; 1.2462x over previous
//
#include <hip/hip_runtime.h>
#include <hip/hip_bf16.h>

#define EPSF 1e-8f

// Workspace layout:
//   x    [loc][c][ci]  bf16, c = cj*4+nj (conv channel order), loc=(b*32+h)*32+w
//                      33,554,432 elems = 64 MiB
//   B    [loc][cj*32+ci] f32, 8,388,608 elems = 32 MiB
//   shat [loc][nj*32+cj] f32, 4 MiB
//   pm/ps/pt [bh=256][ci=32], sm/siz [b=8][ci=32]
// Working set ~101 MB -> L3-resident after first pass.

__device__ __forceinline__ float bflo(unsigned int u) { return __uint_as_float(u << 16); }
__device__ __forceinline__ float bfhi(unsigned int u) { return __uint_as_float(u & 0xffff0000u); }

// ---------------------------------------------------------------------------
// Conv fused with routing iteration 0.
// Conv: Cin=3 (depth taps 8d..8d+2 -> ci=d, n_i 0..2), Cout=128, 3x3, pad 1.
// Iter0: B=0 -> k uniform 1/32768 exactly, so S[loc,u] = (1/32768)*sum_ci x,
// computed via 5-step shfl_xor over the ci half-wave; then squash and
// B1[loc,cj,ci] = sum_nj sh*x. Saves a full 134MB x re-read.
// block 256 = 8 w x 32 ci; grid 1024 = (b,h,wq) for 4 blocks/CU overlap.
__global__ __launch_bounds__(256) void k_convb1(const float* __restrict__ in,
                                                const float* __restrict__ cw,
                                                const float* __restrict__ cb,
                                                __hip_bfloat16* __restrict__ x,
                                                float* __restrict__ B) {
    const int bh = blockIdx.x >> 2;
    const int b = bh >> 5, h = bh & 31;
    const int t = threadIdx.x;
    const int ci = t & 31;
    const int w = ((blockIdx.x & 3) << 3) + (t >> 5);

    float v[27];
#pragma unroll
    for (int kd = 0; kd < 3; ++kd) {
#pragma unroll
        for (int dy = 0; dy < 3; ++dy) {
            const int y = h + dy - 1;
            const bool yok = (y >= 0) && (y < 32);
#pragma unroll
            for (int dx = 0; dx < 3; ++dx) {
                const int xx = w + dx - 1;
                float val = 0.0f;
                if (yok && xx >= 0 && xx < 32)
                    val = in[(((size_t)(b * 32 + ci) * 8 + kd) * 32 + y) * 32 + xx];
                v[kd * 9 + dy * 3 + dx] = val;
            }
        }
    }

    const size_t loc = (size_t)bh * 32 + w;
    __hip_bfloat16* xrow = x + loc * 4096;
    float* Brow = B + loc * 1024;

    for (int cj = 0; cj < 32; ++cj) {       // wave-uniform -> scalar weight loads
        float bacc = 0.0f;
#pragma unroll
        for (int nj = 0; nj < 4; ++nj) {
            const int c = cj * 4 + nj;
            const float* wc = cw + c * 27;
            float acc = cb[c];
#pragma unroll
            for (int k = 0; k < 27; ++k) acc = fmaf(wc[k], v[k], acc);
            // sum over the 32 ci lanes (masks stay within each half-wave group)
            float r = acc;
            r += __shfl_xor(r, 1);  r += __shfl_xor(r, 2);  r += __shfl_xor(r, 4);
            r += __shfl_xor(r, 8);  r += __shfl_xor(r, 16);
            const float S = r * (1.0f / 32768.0f);
            const float sh = fabsf(S) * S / (1.0f + S * S + EPSF);  // squash
            bacc = fmaf(sh, acc, bacc);
            xrow[c * 32 + ci] = __float2bfloat16(acc);
        }
        Brow[cj * 32 + ci] = bacc;           // B starts at 0
    }
}

// ---------------------------------------------------------------------------
// Softmax stats partials: block = (b,h) reduces its 32768-elem slice of B
// into per-ci {max, sum e^{v-m}, sum e^{v-m}(v-m)}.
__global__ __launch_bounds__(256) void k_stats_part(const float* __restrict__ B,
                                                    float* __restrict__ pm,
                                                    float* __restrict__ ps,
                                                    float* __restrict__ pt) {
    const int bh = blockIdx.x;
    const int t = threadIdx.x;
    const float4* Bp = reinterpret_cast<const float4*>(B) + (size_t)bh * 8192;

    float m0 = -1e30f, m1 = -1e30f, m2 = -1e30f, m3 = -1e30f;
#pragma unroll 4
    for (int j = 0; j < 32; ++j) {
        float4 f = Bp[t + j * 256];
        m0 = fmaxf(m0, f.x); m1 = fmaxf(m1, f.y); m2 = fmaxf(m2, f.z); m3 = fmaxf(m3, f.w);
    }
    __shared__ float red[32][33];
    __shared__ float bm[32];
    const int ciq = (t & 7) * 4, copy = t >> 3;
    red[ciq + 0][copy] = m0; red[ciq + 1][copy] = m1;
    red[ciq + 2][copy] = m2; red[ciq + 3][copy] = m3;
    __syncthreads();
    if (t < 32) {
        float M = red[t][0];
        for (int c = 1; c < 32; ++c) M = fmaxf(M, red[t][c]);
        bm[t] = M;
    }
    __syncthreads();
    const float M0 = bm[ciq], M1 = bm[ciq + 1], M2 = bm[ciq + 2], M3 = bm[ciq + 3];

    float s0 = 0, s1 = 0, s2 = 0, s3 = 0, T0 = 0, T1 = 0, T2 = 0, T3 = 0;
#pragma unroll 4
    for (int j = 0; j < 32; ++j) {
        float4 f = Bp[t + j * 256];
        float d, e;
        d = f.x - M0; e = expf(d); s0 += e; T0 += e * d;
        d = f.y - M1; e = expf(d); s1 += e; T1 += e * d;
        d = f.z - M2; e = expf(d); s2 += e; T2 += e * d;
        d = f.w - M3; e = expf(d); s3 += e; T3 += e * d;
    }
    __syncthreads();
    red[ciq + 0][copy] = s0; red[ciq + 1][copy] = s1;
    red[ciq + 2][copy] = s2; red[ciq + 3][copy] = s3;
    __syncthreads();
    if (t < 32) {
        float S = 0;
        for (int c = 0; c < 32; ++c) S += red[t][c];
        ps[bh * 32 + t] = S;
        pm[bh * 32 + t] = bm[t];
    }
    __syncthreads();
    red[ciq + 0][copy] = T0; red[ciq + 1][copy] = T1;
    red[ciq + 2][copy] = T2; red[ciq + 3][copy] = T3;
    __syncthreads();
    if (t < 32) {
        float S = 0;
        for (int c = 0; c < 32; ++c) S += red[t][c];
        pt[bh * 32 + t] = S;
    }
}

// Combine 32 h-partials per (b,ci); optionally emit normalized entropy scalar.
__global__ __launch_bounds__(256) void k_stats_comb(const float* __restrict__ pm,
                                                    const float* __restrict__ ps,
                                                    const float* __restrict__ pt,
                                                    float* __restrict__ sm,
                                                    float* __restrict__ siz,
                                                    float* __restrict__ d_ent,
                                                    int final_) {
    const int t = threadIdx.x;            // t = b*32+ci
    const int b = t >> 5;
    float M = -1e30f;
    for (int h = 0; h < 32; ++h) M = fmaxf(M, pm[(b * 32 + h) * 32 + (t & 31)]);
    float Z = 0.0f, T = 0.0f;
    for (int h = 0; h < 32; ++h) {
        const int i = (b * 32 + h) * 32 + (t & 31);
        const float dm = pm[i] - M;
        const float e = expf(dm);
        Z += ps[i] * e;
        T += e * (pt[i] + ps[i] * dm);
    }
    sm[t] = M;
    siz[t] = 1.0f / Z;
    if (final_) {
        // ent = -sum p log p = logZ - T/Z  (eps-in-log effect ~3e-5, << 2e-2 tol)
        const float ent = (logf(Z) - T / Z) / logf(32768.0f);
        __shared__ float red[256];
        red[t] = ent;
        __syncthreads();
        for (int s2 = 128; s2 > 0; s2 >>= 1) {
            if (t < s2) red[t] += red[t + s2];
            __syncthreads();
        }
        if (t == 0) *d_ent = red[0] * (1.0f / 256.0f);
    }
}

// ---------------------------------------------------------------------------
// Routing iteration (i>=1): k = exp(B-m)/Z on the fly, S, squash; then either
// B += sum_nj sh*x (FINAL=0) or write S_hat (FINAL=1). x is bf16 [loc][c][ci].
template <int FINAL>
__global__ __launch_bounds__(256) void k_iter(const __hip_bfloat16* __restrict__ x,
                                              float* __restrict__ B,
                                              const float* __restrict__ sm,
                                              const float* __restrict__ siz,
                                              float* __restrict__ shat) {
    __shared__ float s_m[32], s_z[32];
    __shared__ float p[2][128][33];
    const int t = threadIdx.x;
    const int bb = (int)(((size_t)blockIdx.x * 2) >> 10);    // batch index
    if (t < 32) { s_m[t] = sm[bb * 32 + t]; s_z[t] = siz[bb * 32 + t]; }
    __syncthreads();

    const int l = t >> 7;
    const int u = t & 127;          // nj*32+cj
    const int cj = u & 31;
    const int c = cj * 4 + (u >> 5);     // conv-order channel for x addressing
    const size_t loc = (size_t)blockIdx.x * 2 + l;

    const uint4* xr = reinterpret_cast<const uint4*>(x + loc * 4096 + (size_t)c * 32);
    const float4* Br = reinterpret_cast<const float4*>(B + loc * 1024 + (size_t)cj * 32);

    uint4 qa = xr[0], qb = xr[1], qc = xr[2], qd = xr[3];
    const unsigned int ua[16] = {qa.x, qa.y, qa.z, qa.w, qb.x, qb.y, qb.z, qb.w,
                                 qc.x, qc.y, qc.z, qc.w, qd.x, qd.y, qd.z, qd.w};
    float xv[32];
#pragma unroll
    for (int k = 0; k < 16; ++k) { xv[2 * k] = bflo(ua[k]); xv[2 * k + 1] = bfhi(ua[k]); }

    float S = 0.0f;
#pragma unroll
    for (int j = 0; j < 8; ++j) {
        float4 bf = Br[j];
        S = fmaf(expf(bf.x - s_m[4 * j + 0]) * s_z[4 * j + 0], xv[4 * j + 0], S);
        S = fmaf(expf(bf.y - s_m[4 * j + 1]) * s_z[4 * j + 1], xv[4 * j + 1], S);
        S = fmaf(expf(bf.z - s_m[4 * j + 2]) * s_z[4 * j + 2], xv[4 * j + 2], S);
        S = fmaf(expf(bf.w - s_m[4 * j + 3]) * s_z[4 * j + 3], xv[4 * j + 3], S);
    }
    const float sh = fabsf(S) * S / (1.0f + S * S + EPSF);

    if constexpr (FINAL) {
        shat[loc * 128 + u] = sh;
    } else {
#pragma unroll
        for (int cc = 0; cc < 32; ++cc) p[l][u][cc] = sh * xv[cc];
        __syncthreads();
#pragma unroll
        for (int r = 0; r < 8; ++r) {
            const int pair = t + r * 256;
            const int l2 = pair >> 10, q = pair & 1023;
            const int cjq = q >> 5, ciq = q & 31;
            const size_t idx = ((size_t)blockIdx.x * 2 + l2) * 1024 + q;
            B[idx] += p[l2][cjq][ciq] + p[l2][32 + cjq][ciq] +
                      p[l2][64 + cjq][ciq] + p[l2][96 + cjq][ciq];
        }
    }
}

// ---------------------------------------------------------------------------
// shat [b][h][w][nj*32+cj]  ->  out [b][cj*4+nj][h][w]
__global__ __launch_bounds__(256) void k_out(const float* __restrict__ shat,
                                             float* __restrict__ out) {
    __shared__ float tile[32][129];   // [w][u]
    const int bh = blockIdx.x;
    const int b = bh >> 5, h = bh & 31;
    const int t = threadIdx.x;
    const float4* sp = reinterpret_cast<const float4*>(shat + (size_t)bh * 4096);
#pragma unroll
    for (int j = 0; j < 4; ++j) {
        const int idx = t + j * 256;           // f4 index, 0..1023
        const float4 f = sp[idx];
        const int w = idx >> 5;
        const int u4 = (idx & 31) * 4;
        tile[w][u4 + 0] = f.x; tile[w][u4 + 1] = f.y;
        tile[w][u4 + 2] = f.z; tile[w][u4 + 3] = f.w;
    }
    __syncthreads();
    const int cp = t >> 1, half = t & 1;            // cp = cj*4+nj
    const int u = (cp & 3) * 32 + (cp >> 2);        // nj*32+cj
    float* op = out + (((size_t)b * 128 + cp) * 32 + h) * 32 + half * 16;
#pragma unroll
    for (int j = 0; j < 16; ++j) op[j] = tile[half * 16 + j][u];
}

// ---------------------------------------------------------------------------
extern "C" void kernel_launch(void* const* d_in, const int* in_sizes, int n_in,
                              void* d_out, int out_size, void* d_ws, size_t ws_size,
                              hipStream_t stream) {
    const float* in = (const float*)d_in[0];   // (8,32,8,32,32)
    const float* cw = (const float*)d_in[1];   // (128,1,3,3,3)
    const float* cb = (const float*)d_in[2];   // (128,)
    float* out = (float*)d_out;                // 1048576 + 1 floats

    __hip_bfloat16* x = (__hip_bfloat16*)d_ws; // 33,554,432 bf16 = 64 MiB
    float* B    = (float*)(x + 33554432);      //  8,388,608 f32 = 32 MiB
    float* shat = B + 8388608;                 //  1,048,576 f32
    float* pm   = shat + 1048576;              //      8,192 f32
    float* ps   = pm + 8192;
    float* pt   = ps + 8192;
    float* sm   = pt + 8192;                   //        256 f32
    float* siz  = sm + 256;                    // total ~101 MB

    k_convb1<<<1024, 256, 0, stream>>>(in, cw, cb, x, B);                  // conv + B1
    k_stats_part<<<256, 256, 0, stream>>>(B, pm, ps, pt);
    k_stats_comb<<<1, 256, 0, stream>>>(pm, ps, pt, sm, siz, out + 1048576, 0);
    k_iter<0><<<4096, 256, 0, stream>>>(x, B, sm, siz, nullptr);           // -> B2
    k_stats_part<<<256, 256, 0, stream>>>(B, pm, ps, pt);
    k_stats_comb<<<1, 256, 0, stream>>>(pm, ps, pt, sm, siz, out + 1048576, 1); // + entropy
    k_iter<1><<<4096, 256, 0, stream>>>(x, B, sm, siz, shat);              // -> S_hat
    k_out<<<256, 256, 0, stream>>>(shat, out);
}